// Round 2
// baseline (304.450 us; speedup 1.0000x reference)
//
#include <hip/hip_runtime.h>
#include <math.h>

#define BB 4
#define RR 8192
#define SS 32
#define IN_DIM 180
#define SLOT_DIM 1536
#define ATT 1536

// ---------------------------------------------------------------------------
// K1: k_ws[b][s][a] += sum_{i in chunk} slot[b][s][i] * Wk[i][a]
// grid (8 s-groups of 4, 6 a-tiles of 256, 8 i-chunks of 192), block 256.
// NEW: 4 s per block -> each Wk element read 8x (was 32x): L2 traffic for
// Wk 302 MB -> 75 MB. sl staged [ii][sg*4+b] (16 floats/ii, broadcast reads).
// k_ws must be zeroed before launch (atomic accumulation over i-chunks).
// ---------------------------------------------------------------------------
__global__ __launch_bounds__(256) void k_proj_kernel(const float* __restrict__ slot,
                                                     const float* __restrict__ Wk,
                                                     float* __restrict__ k_ws) {
    const int ICH = 192;
    __shared__ __align__(16) float sl[ICH * 16];  // 12 KB, [ii][sg*4+b]
    const int s0 = blockIdx.x * 4;
    const int a0 = blockIdx.y * 256;
    const int i0 = blockIdx.z * ICH;
    const int t  = threadIdx.x;

    // bsg-fast mapping: consecutive lanes -> consecutive LDS addresses
    // (conflict-free writes); global side is a 16-row gather, L2-resident.
    for (int idx = t; idx < ICH * 16; idx += 256) {
        int ii = idx >> 4, g = idx & 15;
        int sg = g >> 2, b = g & 3;
        sl[idx] = slot[((size_t)(b * SS + s0 + sg)) * SLOT_DIM + i0 + ii];
    }
    __syncthreads();

    float acc[16];
#pragma unroll
    for (int g = 0; g < 16; ++g) acc[g] = 0.f;

    const int a = a0 + t;
    const float* wkp = Wk + (size_t)i0 * ATT + a;
#pragma unroll 4
    for (int ii = 0; ii < ICH; ++ii) {
        float wk = wkp[(size_t)ii * ATT];
        const float4* sp = (const float4*)(sl + ii * 16);  // wave-broadcast
        const float4 s0v = sp[0], s1v = sp[1], s2v = sp[2], s3v = sp[3];
        acc[0]  += s0v.x * wk; acc[1]  += s0v.y * wk;
        acc[2]  += s0v.z * wk; acc[3]  += s0v.w * wk;
        acc[4]  += s1v.x * wk; acc[5]  += s1v.y * wk;
        acc[6]  += s1v.z * wk; acc[7]  += s1v.w * wk;
        acc[8]  += s2v.x * wk; acc[9]  += s2v.y * wk;
        acc[10] += s2v.z * wk; acc[11] += s2v.w * wk;
        acc[12] += s3v.x * wk; acc[13] += s3v.y * wk;
        acc[14] += s3v.z * wk; acc[15] += s3v.w * wk;
    }
#pragma unroll
    for (int g = 0; g < 16; ++g) {
        int sg = g >> 2, b = g & 3;
        atomicAdd(&k_ws[((size_t)(b * SS + s0 + sg)) * ATT + a], acc[g]);
    }
}

// ---------------------------------------------------------------------------
// K2: M_ws[b][i][s] = scale * sum_a Wq[i][a] * k_ws[b][s][a]
// grid (B*S = 128, 45 i-groups), block 256 = 4 waves. One wave per (i, bs).
// ---------------------------------------------------------------------------
__global__ __launch_bounds__(256) void m_kernel(const float* __restrict__ Wq,
                                                const float* __restrict__ k_ws,
                                                float* __restrict__ M_ws) {
    __shared__ __align__(16) float kr[ATT];  // 6 KB
    const int bs = blockIdx.x;
    const int b = bs / SS, s = bs - b * SS;
    const int t = threadIdx.x;

    for (int idx = t; idx < ATT; idx += 256) kr[idx] = k_ws[(size_t)bs * ATT + idx];
    __syncthreads();

    const int wave = t >> 6, lane = t & 63;
    const int i = blockIdx.y * 4 + wave;  // 45*4 = 180
    const float scale = 0.0255155181f;    // 1536^-0.5

    const float* wq = Wq + (size_t)i * ATT;
    float p = 0.f;
#pragma unroll
    for (int j = 0; j < ATT / 64; ++j) {
        int a = lane + j * 64;
        p += wq[a] * kr[a];
    }
    for (int m = 32; m >= 1; m >>= 1) p += __shfl_xor(p, m, 64);
    if (lane == 0) M_ws[((size_t)b * IN_DIM + i) * SS + s] = p * scale;
}

// ---------------------------------------------------------------------------
// K3: dots = x @ M  -> softmax over s -> write w output.
// grid (R/64, B), block 256. TR=64 rows/tile, 2 rows x 4 slots per thread.
// NEW: softmax fully in-register. Row max/sum reduced over the 8 lanes that
// share a row (shfl_xor 1,2,4); w stored straight to global. The wt LDS
// buffer, two __syncthreads, and the separate write loop are gone.
// ---------------------------------------------------------------------------
__global__ __launch_bounds__(256) void attn_w_kernel(const float* __restrict__ x,
                                                     const float* __restrict__ M_ws,
                                                     float* __restrict__ w_out) {
    const int TR = 64;
    __shared__ __align__(16) float xs[TR * IN_DIM];   // 46 KB
    const int b  = blockIdx.y;
    const int r0 = blockIdx.x * TR;
    const int t  = threadIdx.x;

    {
        const float4* src = (const float4*)(x + ((size_t)b * RR + r0) * IN_DIM);
        float4* dst = (float4*)xs;
        for (int idx = t; idx < TR * IN_DIM / 4; idx += 256) dst[idx] = src[idx];
    }
    __syncthreads();

    const float* Mg = M_ws + (size_t)b * IN_DIM * SS;
    const int rp = t >> 3;             // 0..31 -> rows 2*rp, 2*rp+1
    const int sq = (t & 7) * 4;
    const int ra = rp * 2, rb = ra + 1;
    float4 A = make_float4(0.f, 0.f, 0.f, 0.f);
    float4 Bv = make_float4(0.f, 0.f, 0.f, 0.f);
#pragma unroll 4
    for (int i = 0; i < IN_DIM; ++i) {
        float x0 = xs[ra * IN_DIM + i];
        float x1 = xs[rb * IN_DIM + i];
        const float4 m4 = *(const float4*)(Mg + i * SS + sq);
        A.x += x0 * m4.x; A.y += x0 * m4.y; A.z += x0 * m4.z; A.w += x0 * m4.w;
        Bv.x += x1 * m4.x; Bv.y += x1 * m4.y; Bv.z += x1 * m4.z; Bv.w += x1 * m4.w;
    }

    // In-register softmax. The 8 lanes t = rp*8 + q (q = t&7) jointly hold
    // row ra (in A) and row rb (in Bv); reduce across them with shfl_xor.
    float mA = fmaxf(fmaxf(A.x, A.y), fmaxf(A.z, A.w));
    float mB = fmaxf(fmaxf(Bv.x, Bv.y), fmaxf(Bv.z, Bv.w));
    mA = fmaxf(mA, __shfl_xor(mA, 1, 64));
    mA = fmaxf(mA, __shfl_xor(mA, 2, 64));
    mA = fmaxf(mA, __shfl_xor(mA, 4, 64));
    mB = fmaxf(mB, __shfl_xor(mB, 1, 64));
    mB = fmaxf(mB, __shfl_xor(mB, 2, 64));
    mB = fmaxf(mB, __shfl_xor(mB, 4, 64));

    A.x = __expf(A.x - mA); A.y = __expf(A.y - mA);
    A.z = __expf(A.z - mA); A.w = __expf(A.w - mA);
    Bv.x = __expf(Bv.x - mB); Bv.y = __expf(Bv.y - mB);
    Bv.z = __expf(Bv.z - mB); Bv.w = __expf(Bv.w - mB);

    float sA = A.x + A.y + A.z + A.w;
    float sB = Bv.x + Bv.y + Bv.z + Bv.w;
    sA += __shfl_xor(sA, 1, 64);
    sA += __shfl_xor(sA, 2, 64);
    sA += __shfl_xor(sA, 4, 64);
    sB += __shfl_xor(sB, 1, 64);
    sB += __shfl_xor(sB, 2, 64);
    sB += __shfl_xor(sB, 4, 64);

    const float iA = 1.0f / sA, iB = 1.0f / sB;
    A.x *= iA; A.y *= iA; A.z *= iA; A.w *= iA;
    Bv.x *= iB; Bv.y *= iB; Bv.z *= iB; Bv.w *= iB;

    float* wg = w_out + ((size_t)b * RR + r0) * SS;
    *(float4*)(wg + ra * SS + sq) = A;
    *(float4*)(wg + rb * SS + sq) = Bv;
}

// ---------------------------------------------------------------------------
// K4: s_out[b][r][d] = sum_s w[b][r][s] * slot[b][s][d]
// grid (R/64, 1536/256, B), block 256. Tile 64r x 256d.
// Thread = 16 rows x 4 cols: slot read is one conflict-free b128 (wave reads
// 1 KB contiguous), w reads wave-uniform broadcast, stores 1 KB/instr.
// ---------------------------------------------------------------------------
__global__ __launch_bounds__(256) void out_kernel(const float* __restrict__ slot,
                                                  const float* __restrict__ w_g,
                                                  float* __restrict__ out) {
    const int TRO = 64, TD = 256, WP = 68;
    __shared__ __align__(16) float wtT[SS * WP];  // 8.7 KB, [ss][r] pad 68
    __shared__ __align__(16) float st[SS * TD];   // 32 KB, [ss][d]
    const int b  = blockIdx.z;
    const int r0 = blockIdx.x * TRO;
    const int d0 = blockIdx.y * TD;
    const int t  = threadIdx.x;

    // w tile: 64 rows x 32 slots = 512 float4, transpose into wtT
    {
        const float4* src = (const float4*)(w_g + ((size_t)b * RR + r0) * SS);
#pragma unroll
        for (int k = 0; k < 2; ++k) {
            int idx = t + k * 256;                 // 0..511
            int rr = idx >> 3, ssq = (idx & 7) * 4;
            float4 f = src[idx];
            wtT[(ssq + 0) * WP + rr] = f.x;
            wtT[(ssq + 1) * WP + rr] = f.y;
            wtT[(ssq + 2) * WP + rr] = f.z;
            wtT[(ssq + 3) * WP + rr] = f.w;
        }
    }
    // slot tile: 32 rows x 256 cols = 2048 float4
#pragma unroll
    for (int k = 0; k < 8; ++k) {
        int idx = t + k * 256;                     // 0..2047
        int row = idx >> 6, c4 = (idx & 63) * 4;   // row 0..31, c4 0..252
        *(float4*)(st + row * TD + c4) =
            *(const float4*)(slot + ((size_t)(b * SS + row)) * SLOT_DIM + d0 + c4);
    }
    __syncthreads();

    const int d  = (t & 63) * 4;       // 0..252: wave covers 256 cols contiguously
    const int rg = (t >> 6) * 16;      // 16 rows per thread, uniform per wave
    float4 acc[16];
#pragma unroll
    for (int r = 0; r < 16; ++r) acc[r] = make_float4(0.f, 0.f, 0.f, 0.f);

#pragma unroll 4
    for (int ss = 0; ss < SS; ++ss) {
        const float4 v  = *(const float4*)(st + ss * TD + d);
        const float4 w0 = *(const float4*)(wtT + ss * WP + rg);
        const float4 w1 = *(const float4*)(wtT + ss * WP + rg + 4);
        const float4 w2 = *(const float4*)(wtT + ss * WP + rg + 8);
        const float4 w3 = *(const float4*)(wtT + ss * WP + rg + 12);
        const float wr[16] = {w0.x, w0.y, w0.z, w0.w, w1.x, w1.y, w1.z, w1.w,
                              w2.x, w2.y, w2.z, w2.w, w3.x, w3.y, w3.z, w3.w};
#pragma unroll
        for (int r = 0; r < 16; ++r) {
            acc[r].x += wr[r] * v.x;
            acc[r].y += wr[r] * v.y;
            acc[r].z += wr[r] * v.z;
            acc[r].w += wr[r] * v.w;
        }
    }

#pragma unroll
    for (int r = 0; r < 16; ++r) {
        *(float4*)(out + ((size_t)b * RR + r0 + rg + r) * SLOT_DIM + d0 + d) = acc[r];
    }
}

// ---------------------------------------------------------------------------
extern "C" void kernel_launch(void* const* d_in, const int* in_sizes, int n_in,
                              void* d_out, int out_size, void* d_ws, size_t ws_size,
                              hipStream_t stream) {
    const float* x    = (const float*)d_in[0];  // [4, 8192, 180]
    const float* slot = (const float*)d_in[1];  // [4, 32, 1536]
    const float* Wq   = (const float*)d_in[2];  // [180, 1536]
    const float* Wk   = (const float*)d_in[3];  // [1536, 1536]

    float* out   = (float*)d_out;                        // s: [4, 8192, 1536]
    float* w_out = out + (size_t)BB * RR * SLOT_DIM;     // w: [4, 8192, 32]

    float* k_ws = (float*)d_ws;                          // [4, 32, 1536]
    float* M_ws = k_ws + (size_t)BB * SS * ATT;          // [4, 180, 32]

    // k_ws is accumulated with atomics -> zero it (ws is poisoned 0xAA).
    hipMemsetAsync(k_ws, 0, (size_t)BB * SS * ATT * sizeof(float), stream);

    k_proj_kernel<<<dim3(SS / 4, ATT / 256, SLOT_DIM / 192), 256, 0, stream>>>(slot, Wk, k_ws);
    m_kernel<<<dim3(BB * SS, IN_DIM / 4), 256, 0, stream>>>(Wq, k_ws, M_ws);
    attn_w_kernel<<<dim3(RR / 64, BB), 256, 0, stream>>>(x, M_ws, w_out);
    out_kernel<<<dim3(RR / 64, SLOT_DIM / 256, BB), 256, 0, stream>>>(slot, w_out, out);
}

// Round 3
// 290.962 us; speedup vs baseline: 1.0464x; 1.0464x over previous
//
#include <hip/hip_runtime.h>
#include <math.h>

#define BB 4
#define RR 8192
#define SS 32
#define IN_DIM 180
#define SLOT_DIM 1536
#define ATT 1536

// ---------------------------------------------------------------------------
// K1: k_ws[b][s][a] += sum_{i in chunk} slot[b][s][i] * Wk[i][a]
// grid (32 s, 6 a-tiles of 256, 8 i-chunks of 192), block 256.
// REVERTED to the R1 form (R2's 4-s blocking regressed: uncoalesced 16-row
// gather staging + 384-block grid with 16-deep FMA chains lost ~16 µs).
// sl staged TRANSPOSED: sl[ii][b] -> one broadcast b128 read per iter.
// k_ws must be zeroed before launch (atomic accumulation over i-chunks).
// ---------------------------------------------------------------------------
__global__ __launch_bounds__(256) void k_proj_kernel(const float* __restrict__ slot,
                                                     const float* __restrict__ Wk,
                                                     float* __restrict__ k_ws) {
    const int ICH = 192;
    __shared__ __align__(16) float sl[ICH * BB];  // 3 KB, [ii][b]
    const int s  = blockIdx.x;
    const int a0 = blockIdx.y * 256;
    const int i0 = blockIdx.z * ICH;
    const int t  = threadIdx.x;

    for (int idx = t; idx < BB * ICH; idx += 256) {
        int b = idx / ICH, ii = idx - b * ICH;
        sl[ii * BB + b] = slot[((size_t)(b * SS + s)) * SLOT_DIM + i0 + ii];
    }
    __syncthreads();

    float acc0 = 0.f, acc1 = 0.f, acc2 = 0.f, acc3 = 0.f;
    const int a = a0 + t;
    const float* wkp = Wk + (size_t)i0 * ATT + a;
#pragma unroll 8
    for (int ii = 0; ii < ICH; ++ii) {
        float wk = wkp[(size_t)ii * ATT];
        const float4 s4 = *(const float4*)(sl + ii * BB);
        acc0 += s4.x * wk;
        acc1 += s4.y * wk;
        acc2 += s4.z * wk;
        acc3 += s4.w * wk;
    }
    atomicAdd(&k_ws[((size_t)(0 * SS + s)) * ATT + a], acc0);
    atomicAdd(&k_ws[((size_t)(1 * SS + s)) * ATT + a], acc1);
    atomicAdd(&k_ws[((size_t)(2 * SS + s)) * ATT + a], acc2);
    atomicAdd(&k_ws[((size_t)(3 * SS + s)) * ATT + a], acc3);
}

// ---------------------------------------------------------------------------
// K2: M_ws[b][i][s] = scale * sum_a Wq[i][a] * k_ws[b][s][a]
// grid (B*S = 128, 45 i-groups), block 256 = 4 waves. One wave per (i, bs).
// ---------------------------------------------------------------------------
__global__ __launch_bounds__(256) void m_kernel(const float* __restrict__ Wq,
                                                const float* __restrict__ k_ws,
                                                float* __restrict__ M_ws) {
    __shared__ __align__(16) float kr[ATT];  // 6 KB
    const int bs = blockIdx.x;
    const int b = bs / SS, s = bs - b * SS;
    const int t = threadIdx.x;

    for (int idx = t; idx < ATT; idx += 256) kr[idx] = k_ws[(size_t)bs * ATT + idx];
    __syncthreads();

    const int wave = t >> 6, lane = t & 63;
    const int i = blockIdx.y * 4 + wave;  // 45*4 = 180
    const float scale = 0.0255155181f;    // 1536^-0.5

    const float* wq = Wq + (size_t)i * ATT;
    float p = 0.f;
#pragma unroll
    for (int j = 0; j < ATT / 64; ++j) {
        int a = lane + j * 64;
        p += wq[a] * kr[a];
    }
    for (int m = 32; m >= 1; m >>= 1) p += __shfl_xor(p, m, 64);
    if (lane == 0) M_ws[((size_t)b * IN_DIM + i) * SS + s] = p * scale;
}

// ---------------------------------------------------------------------------
// K3+K4 FUSED: dots = x @ M -> softmax (in-register) -> w to global AND to
// LDS wtT[ss][r] -> s = w @ slot over 6 d-tiles of 256, reusing the xs
// buffer as the slot tile (xs is dead after the dot loop).
// Kills: w L2 round-trip (4.2 MB write + ~25 MB re-read), K4's w transpose
// staging, one kernel launch. LDS = 46 + 8.7 = 54.7 KB -> 2 blocks/CU.
// grid (R/64, B), block 256.
// ---------------------------------------------------------------------------
__global__ __launch_bounds__(256) void attn_out_kernel(const float* __restrict__ x,
                                                       const float* __restrict__ M_ws,
                                                       const float* __restrict__ slot,
                                                       float* __restrict__ w_out,
                                                       float* __restrict__ s_out) {
    const int TR = 64, TD = 256, WP = 68;
    __shared__ __align__(16) float xs[TR * IN_DIM];   // 46 KB; reused as st[32*256] in phase B
    __shared__ __align__(16) float wtT[SS * WP];      // 8.7 KB, [ss][r] pad 68
    const int b  = blockIdx.y;
    const int r0 = blockIdx.x * TR;
    const int t  = threadIdx.x;

    // ---- Phase A: stage x tile ----
    {
        const float4* src = (const float4*)(x + ((size_t)b * RR + r0) * IN_DIM);
        float4* dst = (float4*)xs;
        for (int idx = t; idx < TR * IN_DIM / 4; idx += 256) dst[idx] = src[idx];
    }
    __syncthreads();

    // dots: 2 rows x 4 slots per thread
    const float* Mg = M_ws + (size_t)b * IN_DIM * SS;
    const int rp = t >> 3;             // 0..31 -> rows 2*rp, 2*rp+1
    const int sq = (t & 7) * 4;
    const int ra = rp * 2, rb = ra + 1;
    float4 A = make_float4(0.f, 0.f, 0.f, 0.f);
    float4 Bv = make_float4(0.f, 0.f, 0.f, 0.f);
#pragma unroll 4
    for (int i = 0; i < IN_DIM; ++i) {
        float x0 = xs[ra * IN_DIM + i];
        float x1 = xs[rb * IN_DIM + i];
        const float4 m4 = *(const float4*)(Mg + i * SS + sq);
        A.x += x0 * m4.x; A.y += x0 * m4.y; A.z += x0 * m4.z; A.w += x0 * m4.w;
        Bv.x += x1 * m4.x; Bv.y += x1 * m4.y; Bv.z += x1 * m4.z; Bv.w += x1 * m4.w;
    }

    // in-register softmax: 8 lanes (t = rp*8+q) share rows ra/rb
    float mA = fmaxf(fmaxf(A.x, A.y), fmaxf(A.z, A.w));
    float mB = fmaxf(fmaxf(Bv.x, Bv.y), fmaxf(Bv.z, Bv.w));
    mA = fmaxf(mA, __shfl_xor(mA, 1, 64));
    mA = fmaxf(mA, __shfl_xor(mA, 2, 64));
    mA = fmaxf(mA, __shfl_xor(mA, 4, 64));
    mB = fmaxf(mB, __shfl_xor(mB, 1, 64));
    mB = fmaxf(mB, __shfl_xor(mB, 2, 64));
    mB = fmaxf(mB, __shfl_xor(mB, 4, 64));

    A.x = __expf(A.x - mA); A.y = __expf(A.y - mA);
    A.z = __expf(A.z - mA); A.w = __expf(A.w - mA);
    Bv.x = __expf(Bv.x - mB); Bv.y = __expf(Bv.y - mB);
    Bv.z = __expf(Bv.z - mB); Bv.w = __expf(Bv.w - mB);

    float sA = A.x + A.y + A.z + A.w;
    float sB = Bv.x + Bv.y + Bv.z + Bv.w;
    sA += __shfl_xor(sA, 1, 64);
    sA += __shfl_xor(sA, 2, 64);
    sA += __shfl_xor(sA, 4, 64);
    sB += __shfl_xor(sB, 1, 64);
    sB += __shfl_xor(sB, 2, 64);
    sB += __shfl_xor(sB, 4, 64);

    const float iA = 1.0f / sA, iB = 1.0f / sB;
    A.x *= iA; A.y *= iA; A.z *= iA; A.w *= iA;
    Bv.x *= iB; Bv.y *= iB; Bv.z *= iB; Bv.w *= iB;

    // w output (required by reference): strided float4 stores, 4.2 MB total
    {
        float* wg = w_out + ((size_t)b * RR + r0) * SS;
        *(float4*)(wg + ra * SS + sq) = A;
        *(float4*)(wg + rb * SS + sq) = Bv;
    }

    // deposit w transposed into LDS for the PV phase: wtT[ss][r]
    wtT[(sq + 0) * WP + ra] = A.x;  wtT[(sq + 1) * WP + ra] = A.y;
    wtT[(sq + 2) * WP + ra] = A.z;  wtT[(sq + 3) * WP + ra] = A.w;
    wtT[(sq + 0) * WP + rb] = Bv.x; wtT[(sq + 1) * WP + rb] = Bv.y;
    wtT[(sq + 2) * WP + rb] = Bv.z; wtT[(sq + 3) * WP + rb] = Bv.w;

    // one barrier: wtT visible AND all xs reads (dot loop) retired
    __syncthreads();

    // ---- Phase B: s = w @ slot, 6 d-tiles of 256, st aliases xs ----
    float* st = xs;
    const int d  = (t & 63) * 4;       // wave covers 256 cols contiguously
    const int rg = (t >> 6) * 16;      // 16 rows per thread, uniform per wave

    for (int dt = 0; dt < SLOT_DIM / TD; ++dt) {
        const int d0 = dt * TD;
        // stage slot tile: 32 rows x 256 cols = 2048 float4
#pragma unroll
        for (int k = 0; k < 8; ++k) {
            int idx = t + k * 256;                     // 0..2047
            int row = idx >> 6, c4 = (idx & 63) * 4;   // row 0..31, c4 0..252
            *(float4*)(st + row * TD + c4) =
                *(const float4*)(slot + ((size_t)(b * SS + row)) * SLOT_DIM + d0 + c4);
        }
        __syncthreads();

        float4 acc[16];
#pragma unroll
        for (int r = 0; r < 16; ++r) acc[r] = make_float4(0.f, 0.f, 0.f, 0.f);

#pragma unroll 4
        for (int ss = 0; ss < SS; ++ss) {
            const float4 v  = *(const float4*)(st + ss * TD + d);
            const float4 w0 = *(const float4*)(wtT + ss * WP + rg);
            const float4 w1 = *(const float4*)(wtT + ss * WP + rg + 4);
            const float4 w2 = *(const float4*)(wtT + ss * WP + rg + 8);
            const float4 w3 = *(const float4*)(wtT + ss * WP + rg + 12);
            const float wr[16] = {w0.x, w0.y, w0.z, w0.w, w1.x, w1.y, w1.z, w1.w,
                                  w2.x, w2.y, w2.z, w2.w, w3.x, w3.y, w3.z, w3.w};
#pragma unroll
            for (int r = 0; r < 16; ++r) {
                acc[r].x += wr[r] * v.x;
                acc[r].y += wr[r] * v.y;
                acc[r].z += wr[r] * v.z;
                acc[r].w += wr[r] * v.w;
            }
        }

#pragma unroll
        for (int r = 0; r < 16; ++r) {
            *(float4*)(s_out + ((size_t)b * RR + r0 + rg + r) * SLOT_DIM + d0 + d) = acc[r];
        }
        __syncthreads();   // st reads done before next tile's stores
    }
}

// ---------------------------------------------------------------------------
extern "C" void kernel_launch(void* const* d_in, const int* in_sizes, int n_in,
                              void* d_out, int out_size, void* d_ws, size_t ws_size,
                              hipStream_t stream) {
    const float* x    = (const float*)d_in[0];  // [4, 8192, 180]
    const float* slot = (const float*)d_in[1];  // [4, 32, 1536]
    const float* Wq   = (const float*)d_in[2];  // [180, 1536]
    const float* Wk   = (const float*)d_in[3];  // [1536, 1536]

    float* out   = (float*)d_out;                        // s: [4, 8192, 1536]
    float* w_out = out + (size_t)BB * RR * SLOT_DIM;     // w: [4, 8192, 32]

    float* k_ws = (float*)d_ws;                          // [4, 32, 1536]
    float* M_ws = k_ws + (size_t)BB * SS * ATT;          // [4, 180, 32]

    // k_ws is accumulated with atomics -> zero it (ws is poisoned 0xAA).
    hipMemsetAsync(k_ws, 0, (size_t)BB * SS * ATT * sizeof(float), stream);

    k_proj_kernel<<<dim3(SS, ATT / 256, SLOT_DIM / 192), 256, 0, stream>>>(slot, Wk, k_ws);
    m_kernel<<<dim3(BB * SS, IN_DIM / 4), 256, 0, stream>>>(Wq, k_ws, M_ws);
    attn_out_kernel<<<dim3(RR / 64, BB), 256, 0, stream>>>(x, M_ws, slot, w_out, out);
}

// Round 4
// 283.455 us; speedup vs baseline: 1.0741x; 1.0265x over previous
//
#include <hip/hip_runtime.h>
#include <math.h>

#define BB 4
#define RR 8192
#define SS 32
#define IN_DIM 180
#define SLOT_DIM 1536
#define ATT 1536

// ---------------------------------------------------------------------------
// K1: k_ws[b][s][a] += sum_{i in chunk} slot[b][s][i] * Wk[i][a]
// grid (32 s, 6 a-tiles of 256, 8 i-chunks of 192), block 256.  [R1-exact]
// sl staged TRANSPOSED: sl[ii][b] -> one broadcast b128 read per iter.
// k_ws must be zeroed before launch (atomic accumulation over i-chunks).
// ---------------------------------------------------------------------------
__global__ __launch_bounds__(256) void k_proj_kernel(const float* __restrict__ slot,
                                                     const float* __restrict__ Wk,
                                                     float* __restrict__ k_ws) {
    const int ICH = 192;
    __shared__ __align__(16) float sl[ICH * BB];  // 3 KB, [ii][b]
    const int s  = blockIdx.x;
    const int a0 = blockIdx.y * 256;
    const int i0 = blockIdx.z * ICH;
    const int t  = threadIdx.x;

    for (int idx = t; idx < BB * ICH; idx += 256) {
        int b = idx / ICH, ii = idx - b * ICH;
        sl[ii * BB + b] = slot[((size_t)(b * SS + s)) * SLOT_DIM + i0 + ii];
    }
    __syncthreads();

    float acc0 = 0.f, acc1 = 0.f, acc2 = 0.f, acc3 = 0.f;
    const int a = a0 + t;
    const float* wkp = Wk + (size_t)i0 * ATT + a;
#pragma unroll 8
    for (int ii = 0; ii < ICH; ++ii) {
        float wk = wkp[(size_t)ii * ATT];
        const float4 s4 = *(const float4*)(sl + ii * BB);
        acc0 += s4.x * wk;
        acc1 += s4.y * wk;
        acc2 += s4.z * wk;
        acc3 += s4.w * wk;
    }
    atomicAdd(&k_ws[((size_t)(0 * SS + s)) * ATT + a], acc0);
    atomicAdd(&k_ws[((size_t)(1 * SS + s)) * ATT + a], acc1);
    atomicAdd(&k_ws[((size_t)(2 * SS + s)) * ATT + a], acc2);
    atomicAdd(&k_ws[((size_t)(3 * SS + s)) * ATT + a], acc3);
}

// ---------------------------------------------------------------------------
// K2: M_ws[b][i][s] = scale * sum_a Wq[i][a] * k_ws[b][s][a]
// NEW: grid (32 bs-groups of 4, 45 i-groups of 4), block 256 = 4 waves.
// Block stages FOUR k rows (24 KB); each wave owns one i and dots its Wq row
// against all 4 k rows. Wq L2 traffic 141 MB -> 34.6 MB, k_ws 35 -> 34.6 MB
// (total 176 -> 69 MB). All loads float4, wave reads 1 KB contiguous
// (conflict-free); kr rows are 6 KB apart -> same bank pattern, no conflict.
// ---------------------------------------------------------------------------
__global__ __launch_bounds__(256) void m_kernel(const float* __restrict__ Wq,
                                                const float* __restrict__ k_ws,
                                                float* __restrict__ M_ws) {
    __shared__ __align__(16) float kr[4 * ATT];  // 24 KB, rows bs0..bs0+3
    const int bs0 = blockIdx.x * 4;
    const int t   = threadIdx.x;

    {
        const float4* src = (const float4*)(k_ws + (size_t)bs0 * ATT);
        float4* dst = (float4*)kr;
        for (int idx = t; idx < 4 * ATT / 4; idx += 256) dst[idx] = src[idx];
    }
    __syncthreads();

    const int wave = t >> 6, lane = t & 63;
    const int i = blockIdx.y * 4 + wave;  // 45*4 = 180
    const float scale = 0.0255155181f;    // 1536^-0.5

    const float* wq = Wq + (size_t)i * ATT;
    float p0 = 0.f, p1 = 0.f, p2 = 0.f, p3 = 0.f;
#pragma unroll
    for (int j = 0; j < ATT / 256; ++j) {          // 6 iters
        const int a = lane * 4 + j * 256;
        const float4 w4 = *(const float4*)(wq + a);
        const float4 k0 = *(const float4*)(kr + 0 * ATT + a);
        const float4 k1 = *(const float4*)(kr + 1 * ATT + a);
        const float4 k2 = *(const float4*)(kr + 2 * ATT + a);
        const float4 k3 = *(const float4*)(kr + 3 * ATT + a);
        p0 += w4.x * k0.x + w4.y * k0.y + w4.z * k0.z + w4.w * k0.w;
        p1 += w4.x * k1.x + w4.y * k1.y + w4.z * k1.z + w4.w * k1.w;
        p2 += w4.x * k2.x + w4.y * k2.y + w4.z * k2.z + w4.w * k2.w;
        p3 += w4.x * k3.x + w4.y * k3.y + w4.z * k3.z + w4.w * k3.w;
    }
    for (int m = 32; m >= 1; m >>= 1) {
        p0 += __shfl_xor(p0, m, 64);
        p1 += __shfl_xor(p1, m, 64);
        p2 += __shfl_xor(p2, m, 64);
        p3 += __shfl_xor(p3, m, 64);
    }
    if (lane == 0) {
        const int b = bs0 >> 5;            // bs0 multiple of 4 -> no b straddle
        const int s = bs0 & (SS - 1);
        float* mp = M_ws + ((size_t)b * IN_DIM + i) * SS + s;
        mp[0] = p0 * scale;
        mp[1] = p1 * scale;
        mp[2] = p2 * scale;
        mp[3] = p3 * scale;
    }
}

// ---------------------------------------------------------------------------
// K3: dots = x @ M -> softmax over s -> write w.  [R1-exact]
// grid (R/64, B), block 256. Wave-parallel softmax (4 threads/row via LDS wt).
// ---------------------------------------------------------------------------
__global__ __launch_bounds__(256) void attn_w_kernel(const float* __restrict__ x,
                                                     const float* __restrict__ M_ws,
                                                     float* __restrict__ w_out) {
    const int TR = 64;
    __shared__ __align__(16) float xs[TR * IN_DIM];   // 46 KB
    __shared__ __align__(16) float wt[TR * 33];       // padded, 8.4 KB
    const int b  = blockIdx.y;
    const int r0 = blockIdx.x * TR;
    const int t  = threadIdx.x;

    {
        const float4* src = (const float4*)(x + ((size_t)b * RR + r0) * IN_DIM);
        float4* dst = (float4*)xs;
        for (int idx = t; idx < TR * IN_DIM / 4; idx += 256) dst[idx] = src[idx];
    }
    __syncthreads();

    const float* Mg = M_ws + (size_t)b * IN_DIM * SS;
    const int rp = t >> 3;             // 0..31 -> rows 2*rp, 2*rp+1
    const int sq = (t & 7) * 4;
    const int ra = rp * 2, rb = ra + 1;
    float4 A = make_float4(0.f, 0.f, 0.f, 0.f);
    float4 Bv = make_float4(0.f, 0.f, 0.f, 0.f);
#pragma unroll 4
    for (int i = 0; i < IN_DIM; ++i) {
        float x0 = xs[ra * IN_DIM + i];
        float x1 = xs[rb * IN_DIM + i];
        const float4 m4 = *(const float4*)(Mg + i * SS + sq);
        A.x += x0 * m4.x; A.y += x0 * m4.y; A.z += x0 * m4.z; A.w += x0 * m4.w;
        Bv.x += x1 * m4.x; Bv.y += x1 * m4.y; Bv.z += x1 * m4.z; Bv.w += x1 * m4.w;
    }
    wt[ra * 33 + sq + 0] = A.x;  wt[ra * 33 + sq + 1] = A.y;
    wt[ra * 33 + sq + 2] = A.z;  wt[ra * 33 + sq + 3] = A.w;
    wt[rb * 33 + sq + 0] = Bv.x; wt[rb * 33 + sq + 1] = Bv.y;
    wt[rb * 33 + sq + 2] = Bv.z; wt[rb * 33 + sq + 3] = Bv.w;
    __syncthreads();

    {
        const int row = t >> 2;
        const int j0  = (t & 3) * 8;
        float* wr = wt + row * 33 + j0;
        float mx = -1e30f;
#pragma unroll
        for (int j = 0; j < 8; ++j) mx = fmaxf(mx, wr[j]);
        mx = fmaxf(mx, __shfl_xor(mx, 1, 64));
        mx = fmaxf(mx, __shfl_xor(mx, 2, 64));
        float sum = 0.f;
#pragma unroll
        for (int j = 0; j < 8; ++j) {
            float e = __expf(wr[j] - mx);
            wr[j] = e;
            sum += e;
        }
        sum += __shfl_xor(sum, 1, 64);
        sum += __shfl_xor(sum, 2, 64);
        float inv = 1.0f / sum;
#pragma unroll
        for (int j = 0; j < 8; ++j) wr[j] *= inv;
    }
    __syncthreads();

    float* wg = w_out + ((size_t)b * RR + r0) * SS;
    for (int idx = t; idx < TR * SS; idx += 256) {
        int rr = idx >> 5, ss = idx & 31;
        wg[idx] = wt[rr * 33 + ss];
    }
}

// ---------------------------------------------------------------------------
// K4: s_out[b][r][d] = sum_s w[b][r][s] * slot[b][s][d]  [R1-exact]
// grid (R/64, 1536/256, B), block 256. Thread = 16 rows x 4 cols: slot read
// one conflict-free b128 (wave reads 1 KB contiguous), w reads wave-uniform
// broadcast, stores 1 KB/instr.
// ---------------------------------------------------------------------------
__global__ __launch_bounds__(256) void out_kernel(const float* __restrict__ slot,
                                                  const float* __restrict__ w_g,
                                                  float* __restrict__ out) {
    const int TRO = 64, TD = 256, WP = 68;
    __shared__ __align__(16) float wtT[SS * WP];  // 8.7 KB, [ss][r] pad 68
    __shared__ __align__(16) float st[SS * TD];   // 32 KB, [ss][d]
    const int b  = blockIdx.z;
    const int r0 = blockIdx.x * TRO;
    const int d0 = blockIdx.y * TD;
    const int t  = threadIdx.x;

    {
        const float4* src = (const float4*)(w_g + ((size_t)b * RR + r0) * SS);
#pragma unroll
        for (int k = 0; k < 2; ++k) {
            int idx = t + k * 256;                 // 0..511
            int rr = idx >> 3, ssq = (idx & 7) * 4;
            float4 f = src[idx];
            wtT[(ssq + 0) * WP + rr] = f.x;
            wtT[(ssq + 1) * WP + rr] = f.y;
            wtT[(ssq + 2) * WP + rr] = f.z;
            wtT[(ssq + 3) * WP + rr] = f.w;
        }
    }
#pragma unroll
    for (int k = 0; k < 8; ++k) {
        int idx = t + k * 256;                     // 0..2047
        int row = idx >> 6, c4 = (idx & 63) * 4;   // row 0..31, c4 0..252
        *(float4*)(st + row * TD + c4) =
            *(const float4*)(slot + ((size_t)(b * SS + row)) * SLOT_DIM + d0 + c4);
    }
    __syncthreads();

    const int d  = (t & 63) * 4;       // 0..252: wave covers 256 cols contiguously
    const int rg = (t >> 6) * 16;      // 16 rows per thread, uniform per wave
    float4 acc[16];
#pragma unroll
    for (int r = 0; r < 16; ++r) acc[r] = make_float4(0.f, 0.f, 0.f, 0.f);

#pragma unroll 4
    for (int ss = 0; ss < SS; ++ss) {
        const float4 v  = *(const float4*)(st + ss * TD + d);
        const float4 w0 = *(const float4*)(wtT + ss * WP + rg);
        const float4 w1 = *(const float4*)(wtT + ss * WP + rg + 4);
        const float4 w2 = *(const float4*)(wtT + ss * WP + rg + 8);
        const float4 w3 = *(const float4*)(wtT + ss * WP + rg + 12);
        const float wr[16] = {w0.x, w0.y, w0.z, w0.w, w1.x, w1.y, w1.z, w1.w,
                              w2.x, w2.y, w2.z, w2.w, w3.x, w3.y, w3.z, w3.w};
#pragma unroll
        for (int r = 0; r < 16; ++r) {
            acc[r].x += wr[r] * v.x;
            acc[r].y += wr[r] * v.y;
            acc[r].z += wr[r] * v.z;
            acc[r].w += wr[r] * v.w;
        }
    }

#pragma unroll
    for (int r = 0; r < 16; ++r) {
        *(float4*)(out + ((size_t)b * RR + r0 + rg + r) * SLOT_DIM + d0 + d) = acc[r];
    }
}

// ---------------------------------------------------------------------------
extern "C" void kernel_launch(void* const* d_in, const int* in_sizes, int n_in,
                              void* d_out, int out_size, void* d_ws, size_t ws_size,
                              hipStream_t stream) {
    const float* x    = (const float*)d_in[0];  // [4, 8192, 180]
    const float* slot = (const float*)d_in[1];  // [4, 32, 1536]
    const float* Wq   = (const float*)d_in[2];  // [180, 1536]
    const float* Wk   = (const float*)d_in[3];  // [1536, 1536]

    float* out   = (float*)d_out;                        // s: [4, 8192, 1536]
    float* w_out = out + (size_t)BB * RR * SLOT_DIM;     // w: [4, 8192, 32]

    float* k_ws = (float*)d_ws;                          // [4, 32, 1536]
    float* M_ws = k_ws + (size_t)BB * SS * ATT;          // [4, 180, 32]

    // k_ws is accumulated with atomics -> zero it (ws is poisoned 0xAA).
    hipMemsetAsync(k_ws, 0, (size_t)BB * SS * ATT * sizeof(float), stream);

    k_proj_kernel<<<dim3(SS, ATT / 256, SLOT_DIM / 192), 256, 0, stream>>>(slot, Wk, k_ws);
    m_kernel<<<dim3(BB * SS / 4, IN_DIM / 4), 256, 0, stream>>>(Wq, k_ws, M_ws);
    attn_w_kernel<<<dim3(RR / 64, BB), 256, 0, stream>>>(x, M_ws, w_out);
    out_kernel<<<dim3(RR / 64, SLOT_DIM / 256, BB), 256, 0, stream>>>(slot, w_out, out);
}